// Round 4
// baseline (260.692 us; speedup 1.0000x reference)
//
#include <hip/hip_runtime.h>

// Differential attention, fused flash-style, f16 MFMA, S^T orientation (gfx950).
// B=4, T=1024, 16 head-pairs (32 QK heads), D_HEAD=64, V dim=128, causal.
//
// R3: XCD co-location swizzle (8 blocks sharing (b,hp) -> same XCD so K/V is
// L2-resident; FETCH was 2.2x ideal); double-buffered LDS with ONE barrier
// per iteration (write t+1 into buf^1 while computing t); wave-uniform
// alpha==1 skip for the O rescale.

typedef _Float16 f16x4 __attribute__((ext_vector_type(4)));
typedef _Float16 f16x8 __attribute__((ext_vector_type(8)));
typedef float    f32x4 __attribute__((ext_vector_type(4)));

constexpr int   TSEQ        = 1024;
constexpr int   DQK         = 64;
constexpr int   DVDIM       = 128;
constexpr float SCALING     = 0.125f;                 // 1/sqrt(64)
constexpr float LAMBDA_INIT = 0.7836057665316245f;    // 0.8 - 0.6*exp(-3.6)
constexpr float ONE_MINUS_LI= 1.0f - LAMBDA_INIT;
constexpr float RMS_EPS     = 1e-6f;
constexpr float LOG2E       = 1.4426950408889634f;

__global__ __launch_bounds__(256, 2)
void diff_attn_kernel(const float* __restrict__ qg, const float* __restrict__ kg,
                      const float* __restrict__ vg,
                      const float* __restrict__ lq1, const float* __restrict__ lk1,
                      const float* __restrict__ lq2, const float* __restrict__ lk2,
                      const float* __restrict__ rmsw, float* __restrict__ out)
{
    // double-buffered tiles: K (2 heads x 64 s x 64 d, rows 64->72 halves),
    // V^T [dv][s] rows 64->68 halves, column-rotation swizzled. 71680 B total.
    __shared__ _Float16 Klds[2][2][64][72];
    __shared__ _Float16 Vt[2][128][68];

    // ---- XCD co-location: sharers of (b,hp) get ids == same value mod 8 ----
    const int lin = blockIdx.x;          // grid = (512,1,1)
    const int xs  = lin & 7;             // XCD slot (round-robin assumption)
    const int a   = (lin >> 3) & 7;      // pair index -> q-tiles {a, 15-a}
    const int g   = xs + ((lin >> 6) << 3);   // group 0..63
    const int hp  = g & 15;
    const int b   = g >> 4;

    const int t    = threadIdx.x;
    const int w    = t >> 6;
    const int lane = t & 63;
    const int n    = lane & 15;    // col index of C (q); m of A-frags
    const int quad = lane >> 4;

    // ---- lambda_final: wave-parallel dot + butterfly reduce ----
    float a1 = lq1[hp*64 + lane] * lk1[hp*64 + lane];
    float a2 = lq2[hp*64 + lane] * lk2[hp*64 + lane];
    #pragma unroll
    for (int d = 1; d < 64; d <<= 1) { a1 += __shfl_xor(a1, d); a2 += __shfl_xor(a2, d); }
    const float lambda = __expf(a1) - __expf(a2) + LAMBDA_INIT;

    const float* kb = kg + ((size_t)(b*32 + hp*2)) * TSEQ * DQK;
    const float* vb = vg + ((size_t)(b*16 + hp))   * TSEQ * DVDIM;

    // ---- staging geometry ----
    const int jj   = t & 15;            // V: dv-block owner
    const int sg   = t >> 4;            // V: s-group
    const int dvb  = jj * 8;
    const int s0   = sg * 4;
    const int rotw = (jj & 7) * 8;      // V write swizzle rotation (halves)
    const int d8   = t & 7;             // K: d-chunk

    float4 kr[4][2], vr[8];

    auto load_tile = [&](int sbase) {
        #pragma unroll
        for (int i = 0; i < 4; ++i) {
            const int row = (i*256 + t) >> 3;        // 0..127 (h*64 + s)
            const int h = row >> 6, sr = row & 63;
            const float* p = kb + ((size_t)h*TSEQ + sbase + sr)*DQK + d8*8;
            kr[i][0] = *(const float4*)p;
            kr[i][1] = *(const float4*)(p + 4);
        }
        const float* vp = vb + (size_t)(sbase + s0)*DVDIM + dvb;
        #pragma unroll
        for (int r = 0; r < 4; ++r) {
            vr[2*r]   = *(const float4*)(vp + r*DVDIM);
            vr[2*r+1] = *(const float4*)(vp + r*DVDIM + 4);
        }
    };

    auto write_tile = [&](int bi) {
        #pragma unroll
        for (int i = 0; i < 4; ++i) {
            const int row = (i*256 + t) >> 3;
            const int h = row >> 6, sr = row & 63;
            f16x8 kk;
            kk[0]=(_Float16)kr[i][0].x; kk[1]=(_Float16)kr[i][0].y;
            kk[2]=(_Float16)kr[i][0].z; kk[3]=(_Float16)kr[i][0].w;
            kk[4]=(_Float16)kr[i][1].x; kk[5]=(_Float16)kr[i][1].y;
            kk[6]=(_Float16)kr[i][1].z; kk[7]=(_Float16)kr[i][1].w;
            *(f16x8*)&Klds[bi][h][sr][d8*8] = kk;
        }
        float vrow[4][8];
        #pragma unroll
        for (int r = 0; r < 4; ++r) {
            vrow[r][0]=vr[2*r].x;   vrow[r][1]=vr[2*r].y;
            vrow[r][2]=vr[2*r].z;   vrow[r][3]=vr[2*r].w;
            vrow[r][4]=vr[2*r+1].x; vrow[r][5]=vr[2*r+1].y;
            vrow[r][6]=vr[2*r+1].z; vrow[r][7]=vr[2*r+1].w;
        }
        #pragma unroll
        for (int mI = 0; mI < 8; ++mI) {
            f16x4 pk;
            pk[0]=(_Float16)vrow[0][mI]; pk[1]=(_Float16)vrow[1][mI];
            pk[2]=(_Float16)vrow[2][mI]; pk[3]=(_Float16)vrow[3][mI];
            *(f16x4*)&Vt[bi][dvb + mI][(s0 + rotw) & 63] = pk;
        }
    };

    const float qscale = SCALING * LOG2E;
    load_tile(0);
    int gi = 0;   // global iteration counter (buffer parity)

    for (int part = 0; part < 2; ++part) {
        const int qt    = part ? (15 - a) : a;
        const int qbase = qt * 64;
        const int qw0   = qbase + w * 16;
        const int qrow  = qw0 + n;
        const int nT    = qt + 1;

        // Q fragments (B-operand of S^T MFMA), pre-scaled into exp2 domain
        f16x8 Qf[2][2];
        #pragma unroll
        for (int h = 0; h < 2; ++h) {
            const float* qp = qg + (((size_t)(b*32 + hp*2 + h)) * TSEQ + qrow) * DQK + quad*8;
            #pragma unroll
            for (int ks = 0; ks < 2; ++ks) {
                float4 x = *(const float4*)(qp + ks*32);
                float4 y = *(const float4*)(qp + ks*32 + 4);
                f16x8 f;
                f[0]=(_Float16)(x.x*qscale); f[1]=(_Float16)(x.y*qscale);
                f[2]=(_Float16)(x.z*qscale); f[3]=(_Float16)(x.w*qscale);
                f[4]=(_Float16)(y.x*qscale); f[5]=(_Float16)(y.y*qscale);
                f[6]=(_Float16)(y.z*qscale); f[7]=(_Float16)(y.w*qscale);
                Qf[h][ks] = f;
            }
        }

        f32x4 O[2][8];
        #pragma unroll
        for (int h = 0; h < 2; ++h)
            #pragma unroll
            for (int d = 0; d < 8; ++d) O[h][d] = (f32x4){0.f,0.f,0.f,0.f};
        float m_[2] = { -__builtin_huge_valf(), -__builtin_huge_valf() };
        float l_[2] = { 0.f, 0.f };

        for (int tile = 0; tile < nT; ++tile, ++gi) {
            const int sbase = tile * 64;
            const int bi    = gi & 1;

            write_tile(bi);       // stage tile `tile` into current buffer
            __syncthreads();      // writes visible; prior readers of buf^1 done
            if (tile + 1 < nT)  load_tile((tile + 1) * 64);  // prefetch
            else if (part == 0) load_tile(0);                // part 1 tile 0

            const bool diag = (tile == qt);
            const int  nact = diag ? (w + 1) : 4;   // active 16-s sub-tiles

            f16x4 pb[2][4];
            #pragma unroll
            for (int h = 0; h < 2; ++h) {
                f32x4 St[4];
                #pragma unroll
                for (int sub = 0; sub < 4; ++sub) {
                    if (sub < nact) {
                        f16x8 k0 = *(const f16x8*)&Klds[bi][h][sub*16 + n][quad*8];
                        f16x8 k1 = *(const f16x8*)&Klds[bi][h][sub*16 + n][32 + quad*8];
                        f32x4 c = (f32x4){0.f,0.f,0.f,0.f};
                        c = __builtin_amdgcn_mfma_f32_16x16x32_f16(k0, Qf[h][0], c, 0, 0, 0);
                        c = __builtin_amdgcn_mfma_f32_16x16x32_f16(k1, Qf[h][1], c, 0, 0, 0);
                        St[sub] = c;
                    }
                }
                float vals[16];
                #pragma unroll
                for (int sub = 0; sub < 4; ++sub) {
                    if (sub < nact) {
                        #pragma unroll
                        for (int r = 0; r < 4; ++r) {
                            const int s = sbase + sub*16 + quad*4 + r;
                            float x = St[sub][r];
                            if (diag && s > qrow) x = -__builtin_huge_valf();
                            vals[sub*4 + r] = x;
                        }
                    }
                }
                float mx = -__builtin_huge_valf();
                #pragma unroll
                for (int sub = 0; sub < 4; ++sub)
                    if (sub < nact)
                        #pragma unroll
                        for (int r = 0; r < 4; ++r) mx = fmaxf(mx, vals[sub*4 + r]);
                mx = fmaxf(mx, __shfl_xor(mx, 16));
                mx = fmaxf(mx, __shfl_xor(mx, 32));
                const float mold  = m_[h];
                const float mnew  = fmaxf(mold, mx);
                const float alpha = exp2f(mold - mnew);
                float rs = 0.f;
                #pragma unroll
                for (int sub = 0; sub < 4; ++sub) {
                    if (sub < nact) {
                        #pragma unroll
                        for (int r = 0; r < 4; ++r) {
                            const float p = exp2f(vals[sub*4 + r] - mnew);
                            rs += p;
                            pb[h][sub][r] = (_Float16)p;
                        }
                    }
                }
                rs += __shfl_xor(rs, 16);
                rs += __shfl_xor(rs, 32);
                m_[h] = mnew;
                l_[h] = l_[h] * alpha + rs;
                if (!__all(mnew == mold)) {      // skip rescale when alpha==1 wave-wide
                    #pragma unroll
                    for (int d = 0; d < 8; ++d) {
                        O[h][d][0] *= alpha; O[h][d][1] *= alpha;
                        O[h][d][2] *= alpha; O[h][d][3] *= alpha;
                    }
                }
            }
            // PV: O^T += V^T · P^T ; V frags shared by both heads
            #pragma unroll
            for (int dd = 0; dd < 8; ++dd) {
                const int rot_r = ((2*dd + (n >> 3)) & 7) * 8;
                #pragma unroll
                for (int sub = 0; sub < 4; ++sub) {
                    if (sub < nact) {
                        f16x4 va = *(const f16x4*)&Vt[bi][dd*16 + n][(sub*16 + quad*4 + rot_r) & 63];
                        O[0][dd] = __builtin_amdgcn_mfma_f32_16x16x16f16(va, pb[0][sub], O[0][dd], 0, 0, 0);
                        O[1][dd] = __builtin_amdgcn_mfma_f32_16x16x16f16(va, pb[1][sub], O[1][dd], 0, 0, 0);
                    }
                }
            }
        }

        // ---- epilogue: combine heads, RMS over dv=128, scale, store ----
        const float i1 = 1.0f   / l_[0];
        const float i2 = lambda / l_[1];
        float yv[8][4];
        float ss = 0.f;
        #pragma unroll
        for (int d = 0; d < 8; ++d)
            #pragma unroll
            for (int r = 0; r < 4; ++r) {
                const float y = O[0][d][r] * i1 - O[1][d][r] * i2;
                yv[d][r] = y; ss += y * y;
            }
        ss += __shfl_xor(ss, 16);
        ss += __shfl_xor(ss, 32);
        const float sc = rsqrtf(ss * (1.0f/128.0f) + RMS_EPS) * ONE_MINUS_LI;

        float* ob = out + (((size_t)(b*16 + hp)) * TSEQ + qrow) * DVDIM;
        #pragma unroll
        for (int d = 0; d < 8; ++d) {
            const int dv = d*16 + quad*4;
            float4 wv = *(const float4*)&rmsw[dv];
            float4 o;
            o.x = yv[d][0] * sc * wv.x;
            o.y = yv[d][1] * sc * wv.y;
            o.z = yv[d][2] * sc * wv.z;
            o.w = yv[d][3] * sc * wv.w;
            *(float4*)(ob + dv) = o;
        }
    }
}

extern "C" void kernel_launch(void* const* d_in, const int* in_sizes, int n_in,
                              void* d_out, int out_size, void* d_ws, size_t ws_size,
                              hipStream_t stream) {
    const float* q    = (const float*)d_in[0];
    const float* k    = (const float*)d_in[1];
    const float* v    = (const float*)d_in[2];
    // d_in[3] = mask (causal tril, hardcoded), d_in[9] = flash_attn flag (unused)
    const float* lq1  = (const float*)d_in[4];
    const float* lk1  = (const float*)d_in[5];
    const float* lq2  = (const float*)d_in[6];
    const float* lk2  = (const float*)d_in[7];
    const float* rmsw = (const float*)d_in[8];
    float* out = (float*)d_out;

    dim3 grid(512, 1, 1);   // flat; kernel decodes (xcd-slot, pair, group)
    dim3 block(256);
    diff_attn_kernel<<<grid, block, 0, stream>>>(q, k, v, lq1, lk1, lq2, lk2, rmsw, out);
}